// Round 6
// baseline (26845.728 us; speedup 1.0000x reference)
//
#include <hip/hip_runtime.h>

// FFJORD density on MI355X (gfx950). B=65536 rows, DIM=128, HID=512, 32 RK4 steps x 4 evals.
// Round 8: kill the register spill. Round-7 counters: WRITE_SIZE=2.1GB/dispatch with ZERO
// global stores in the eval loop = scratch spill (8 dwords/thread/eval); FETCH=18.7GB is
// spill re-reads + the L2 weight-thrash they cause. Demand was ~135-140 unified vs the
// 128 cap (launch_bounds(512,4)). Fix: un-pin the 13 bias registers (b1/w1t/b2/b3) --
// they are 6KB L2-resident arrays, re-loaded per eval via volatile (prevents LICM from
// re-pinning). Phase C: g2 = g3-(g3*h)*h (2 VALU). Everything else unchanged from R7:
// 32-row blocks, LDS 77.3KB -> 2 blocks/CU, zero state traffic, weights from L2.
//   Z: h1=tanh(zs@W1z+t*w1t+b1)->H1 | A: h2=tanh(h1@W2+b2)->Hs | B: f=h2@W3+b3, z/accf regs,
//   zs->Zs | C: Hs<-g3*(1-h2^2) | D: Hs<-g2@W2^T | E: div=rowsum(Hs*(1-h1^2)*u)->accd/lp regs.

#define DIMV 128
#define HIDV 512
#define ROWS 32
#define PAN_STR 536   // panel stride (shorts): 1072B, 16B-aligned, 12-word bank shift/row
#define ZS_STR  136   // 272B, 16B-aligned

typedef float  floatx4 __attribute__((ext_vector_type(4)));
typedef short  short8  __attribute__((ext_vector_type(8)));

static __device__ __forceinline__ unsigned short f2bf(float x) {
    union { float f; unsigned int u; } c; c.f = x;
    unsigned int u = c.u;
    u += 0x7FFFu + ((u >> 16) & 1u);   // round-to-nearest-even
    return (unsigned short)(u >> 16);
}
static __device__ __forceinline__ float bf2f(unsigned short h) {
    union { unsigned int u; float f; } c; c.u = ((unsigned int)h) << 16;
    return c.f;
}
static __device__ __forceinline__ float fast_tanh(float x) {
    x = fminf(8.0f, fmaxf(-8.0f, x));
    float e = exp2f(x * 2.8853900817779268f);            // exp(2x)
    return (e - 1.0f) * __builtin_amdgcn_rcpf(e + 1.0f); // (e-1)/(e+1)
}

// ---- weight packing: dst[(k>>3)*N*8 + n*8 + (k&7)] = bf16(W[k][n]) ------------
__global__ void pack_kernel(const float* __restrict__ src, unsigned short* __restrict__ dst,
                            int K, int N, int ld, int transpose) {
    int i = blockIdx.x * 256 + threadIdx.x;
    if (i >= K * N) return;
    int j  = i & 7;
    int n  = (i >> 3) % N;
    int k8 = (i >> 3) / N;
    int k  = k8 * 8 + j;
    float v = transpose ? src[n * ld + k] : src[k * ld + n];
    dst[i] = f2bf(v);
}

// ---- v-GEMM producer (g3 = v@W3^T, u = v@W1z): 128 rows x 256 cols per WG -----
__global__ __launch_bounds__(256, 2) void vg_k(const float* __restrict__ v,
                                               const unsigned short* __restrict__ Wp,
                                               unsigned short* __restrict__ out0) {
    __shared__ __align__(16) unsigned short As[128 * 72];
    const int tid  = threadIdx.x;
    const int wave = tid >> 6, lane = tid & 63;
    const int quad = lane >> 4, l16 = lane & 15;
    const int row0 = blockIdx.x * 128;
    const int colw = blockIdx.y * 256 + wave * 64;

    floatx4 acc[8][4];
    #pragma unroll
    for (int m = 0; m < 8; ++m)
        #pragma unroll
        for (int f = 0; f < 4; ++f) { floatx4 zz = {0.f,0.f,0.f,0.f}; acc[m][f] = zz; }

    for (int k0 = 0; k0 < 128; k0 += 64) {
        __syncthreads();
        {
            const int r  = tid >> 3;
            const int cc = (tid & 7) << 3;
            #pragma unroll
            for (int i = 0; i < 4; ++i) {
                const int rr = r + (i << 5);
                const size_t base = (size_t)(row0 + rr) * 128 + k0 + cc;
                float vals[8];
                *(float4*)&vals[0] = *(const float4*)&v[base];
                *(float4*)&vals[4] = *(const float4*)&v[base + 4];
                short8 sv;
                #pragma unroll
                for (int j = 0; j < 8; ++j) sv[j] = (short)f2bf(vals[j]);
                *reinterpret_cast<short8*>(&As[rr * 72 + cc]) = sv;
            }
        }
        __syncthreads();
        #pragma unroll
        for (int kt = 0; kt < 2; ++kt) {
            const int k8 = (k0 >> 3) + (kt << 2) + quad;
            short8 b[4];
            #pragma unroll
            for (int f = 0; f < 4; ++f)
                b[f] = *reinterpret_cast<const short8*>(
                    &Wp[((size_t)k8 * 512 + colw + (f << 4) + l16) << 3]);
            #pragma unroll
            for (int m = 0; m < 8; ++m) {
                const short8 a = *reinterpret_cast<const short8*>(
                    &As[(m * 16 + l16) * 72 + (kt << 5) + (quad << 3)]);
                #pragma unroll
                for (int f = 0; f < 4; ++f)
                    acc[m][f] = __builtin_amdgcn_mfma_f32_16x16x32_bf16(a, b[f], acc[m][f], 0, 0, 0);
            }
        }
    }
    #pragma unroll
    for (int m = 0; m < 8; ++m)
        #pragma unroll
        for (int f = 0; f < 4; ++f) {
            const int col = colw + (f << 4) + l16;
            #pragma unroll
            for (int r = 0; r < 4; ++r) {
                const int row = row0 + m * 16 + quad * 4 + r;
                out0[(size_t)row * 512 + col] = f2bf(acc[m][f][r]);
            }
        }
}

// ---- persistent integrator ----------------------------------------------------
struct OArgs {
    const float* x;              // fp32 input chunk [C,128]
    const unsigned short* W1zp;  // packed (K=128,N=512)
    const unsigned short* W2p;   // packed (K=512,N=512)
    const unsigned short* W3p;   // packed (K=512,N=128)
    const unsigned short* W2Tp;  // packed (K=512,N=512)
    const unsigned short* g3;    // bf16 [C,512]  (per-chunk constant)
    const unsigned short* u;     // bf16 [C,512]  (per-chunk constant)
    const float* b1;
    const float* w1t;            // W1 row 128 (t coefficients)
    const float* b2;
    const float* b3;
    float* z;                    // fp32 [C,128] out (for final_k)
    float* lp;                   // fp32 [C]
};

__global__ __launch_bounds__(512, 4) void ode_k(OArgs p) {
    __shared__ __align__(16) unsigned short H1s[ROWS * PAN_STR]; // 34.3 KB h1 panel
    __shared__ __align__(16) unsigned short Hss[ROWS * PAN_STR]; // 34.3 KB h2/g2/g1' panel
    __shared__ __align__(16) unsigned short Zss[ROWS * ZS_STR];  //  8.7 KB zs panel
    const int tid  = threadIdx.x;
    const int wave = tid >> 6, lane = tid & 63;
    const int quad = lane >> 4, l16 = lane & 15;
    const int row0 = blockIdx.x * ROWS;
    const int colw = wave << 6;          // phases Z/A/D: 64 cols per wave
    const int sr = tid >> 4;             // streaming row 0..31 (16 threads/row)
    const int sc = (tid & 15) << 3;      // streaming col-base (shorts), 128 cols/pass
    const size_t gbase = (size_t)(row0 + sr) * 512;
    const int colB = (wave << 4) + l16;  // phase B column (0..127)

    // volatile bias pointers: re-load per eval, NOT pinned in registers (reg budget)
    volatile const float* vb1 = p.b1;
    volatile const float* vw1t = p.w1t;
    volatile const float* vb2 = p.b2;
    volatile const float* vb3 = p.b3;

    // ---- per-chunk constants pinned in registers (streaming mapping) ----
    short8 g3v[4], uv[4];
    #pragma unroll
    for (int j = 0; j < 4; ++j) {
        g3v[j] = *reinterpret_cast<const short8*>(&p.g3[gbase + sc + (j << 7)]);
        uv[j]  = *reinterpret_cast<const short8*>(&p.u [gbase + sc + (j << 7)]);
    }

    // ---- state in registers (phase-B mapping: row=m*16+quad*4+r, col=colB) ----
    float z_r[2][4];
    #pragma unroll
    for (int m = 0; m < 2; ++m)
        #pragma unroll
        for (int r = 0; r < 4; ++r) {
            const int row = m * 16 + quad * 4 + r;
            const float val = p.x[(size_t)(row0 + row) * 128 + colB];
            z_r[m][r] = val;
            Zss[row * ZS_STR + colB] = f2bf(val);
        }
    float accf_r[2][4];
    float accd_r = 0.0f, lp_r = 0.0f;

    const float dt = 1.0f / 32.0f;
    floatx4 acc[2][4];                   // shared by phases Z/A/D

    for (int e = 0; e < 128; ++e) {
        const int s = e & 3;
        const int step = e >> 2;
        const bool s0 = (s == 0), s3 = (s == 3);
        const float tph  = (s == 0) ? 0.0f : (s == 3 ? dt : 0.5f * dt);
        const float t    = (float)step * dt + tph;
        const float wrk  = (s == 1 || s == 2) ? (dt / 3.0f) : (dt / 6.0f);
        const float cnext = (s <= 1) ? 0.5f * dt : (s == 2 ? dt : 0.0f);

        __syncthreads();   // (1) close prev eval: E's H1s/Hss reads done; Zss writes visible

        // ===== phase Z: h1 = tanh(zs @ W1z + t*w1t + b1) -> H1s ================
        #pragma unroll
        for (int m = 0; m < 2; ++m)
            #pragma unroll
            for (int f = 0; f < 4; ++f) { floatx4 zz = {0.f,0.f,0.f,0.f}; acc[m][f] = zz; }
        #pragma unroll
        for (int kt = 0; kt < 4; ++kt) {
            const int k8 = (kt << 2) + quad;
            short8 b[4];
            #pragma unroll
            for (int f = 0; f < 4; ++f)
                b[f] = *reinterpret_cast<const short8*>(
                    &p.W1zp[((size_t)k8 * 512 + colw + (f << 4) + l16) << 3]);
            #pragma unroll
            for (int m = 0; m < 2; ++m) {
                const short8 a = *reinterpret_cast<const short8*>(
                    &Zss[(m * 16 + l16) * ZS_STR + (kt << 5) + (quad << 3)]);
                #pragma unroll
                for (int f = 0; f < 4; ++f)
                    acc[m][f] = __builtin_amdgcn_mfma_f32_16x16x32_bf16(a, b[f], acc[m][f], 0, 0, 0);
            }
        }
        #pragma unroll
        for (int m = 0; m < 2; ++m)
            #pragma unroll
            for (int f = 0; f < 4; ++f) {
                const int col = colw + (f << 4) + l16;
                const float bias = vb1[col] + t * vw1t[col];   // per-eval load (L2-hot)
                #pragma unroll
                for (int r = 0; r < 4; ++r) {
                    const int row = m * 16 + quad * 4 + r;
                    H1s[row * PAN_STR + col] = f2bf(fast_tanh(acc[m][f][r] + bias));
                }
            }
        __syncthreads();   // (2) H1s ready

        // ===== phase A: h2 = tanh(h1 @ W2 + b2) -> Hss =========================
        #pragma unroll
        for (int m = 0; m < 2; ++m)
            #pragma unroll
            for (int f = 0; f < 4; ++f) { floatx4 zz = {0.f,0.f,0.f,0.f}; acc[m][f] = zz; }
        #pragma unroll 4
        for (int kt = 0; kt < 16; ++kt) {
            const int k8 = (kt << 2) + quad;
            short8 b[4];
            #pragma unroll
            for (int f = 0; f < 4; ++f)
                b[f] = *reinterpret_cast<const short8*>(
                    &p.W2p[((size_t)k8 * 512 + colw + (f << 4) + l16) << 3]);
            #pragma unroll
            for (int m = 0; m < 2; ++m) {
                const short8 a = *reinterpret_cast<const short8*>(
                    &H1s[(m * 16 + l16) * PAN_STR + (kt << 5) + (quad << 3)]);
                #pragma unroll
                for (int f = 0; f < 4; ++f)
                    acc[m][f] = __builtin_amdgcn_mfma_f32_16x16x32_bf16(a, b[f], acc[m][f], 0, 0, 0);
            }
        }
        #pragma unroll
        for (int m = 0; m < 2; ++m)
            #pragma unroll
            for (int f = 0; f < 4; ++f) {
                const int col = colw + (f << 4) + l16;
                const float bias = vb2[col];                   // per-eval load
                #pragma unroll
                for (int r = 0; r < 4; ++r) {
                    const int row = m * 16 + quad * 4 + r;
                    Hss[row * PAN_STR + col] = f2bf(fast_tanh(acc[m][f][r] + bias));
                }
            }
        __syncthreads();   // (3) Hss (h2) ready

        // ===== phase B: f = h2 @ W3 + b3 ; z/accf regs ; zs -> Zss =============
        {
            floatx4 accb[2];
            #pragma unroll
            for (int m = 0; m < 2; ++m) { floatx4 zz = {0.f,0.f,0.f,0.f}; accb[m] = zz; }
            #pragma unroll 4
            for (int kt = 0; kt < 16; ++kt) {
                const int k8 = (kt << 2) + quad;
                const short8 b = *reinterpret_cast<const short8*>(
                    &p.W3p[((size_t)k8 * 128 + colB) << 3]);
                #pragma unroll
                for (int m = 0; m < 2; ++m) {
                    const short8 a = *reinterpret_cast<const short8*>(
                        &Hss[(m * 16 + l16) * PAN_STR + (kt << 5) + (quad << 3)]);
                    accb[m] = __builtin_amdgcn_mfma_f32_16x16x32_bf16(a, b, accb[m], 0, 0, 0);
                }
            }
            const float b3v = vb3[colB];                       // per-eval load
            #pragma unroll
            for (int m = 0; m < 2; ++m) {
                #pragma unroll
                for (int r = 0; r < 4; ++r) {
                    const int row = m * 16 + quad * 4 + r;
                    const float x = accb[m][r] + b3v;
                    const float a = wrk * x + (s0 ? 0.0f : accf_r[m][r]);
                    if (s3) {
                        z_r[m][r] += a;                       // z += dt/6 * sum(k)
                        Zss[row * ZS_STR + colB] = f2bf(z_r[m][r]);
                    } else {
                        accf_r[m][r] = a;
                        Zss[row * ZS_STR + colB] = f2bf(z_r[m][r] + cnext * x);
                    }
                }
            }
        }
        __syncthreads();   // (4) all h2 reads done before in-place C

        // ===== phase C: Hss <- g2 = g3 - (g3*h2)*h2  (pinned g3 regs) ==========
        #pragma unroll
        for (int j = 0; j < 4; ++j) {
            const int cc = sc + (j << 7);
            const short8 hv = *reinterpret_cast<const short8*>(&Hss[sr * PAN_STR + cc]);
            short8 ov;
            #pragma unroll
            for (int el = 0; el < 8; ++el) {
                const float h = bf2f((unsigned short)hv[el]);
                const float g = bf2f((unsigned short)g3v[j][el]);
                const float gh = g * h;
                ov[el] = (short)f2bf(fmaf(-gh, h, g));
            }
            *reinterpret_cast<short8*>(&Hss[sr * PAN_STR + cc]) = ov;
        }
        __syncthreads();   // (5) g2 ready

        // ===== phase D: Hss <- g2 @ W2^T ========================================
        #pragma unroll
        for (int m = 0; m < 2; ++m)
            #pragma unroll
            for (int f = 0; f < 4; ++f) { floatx4 zz = {0.f,0.f,0.f,0.f}; acc[m][f] = zz; }
        #pragma unroll 4
        for (int kt = 0; kt < 16; ++kt) {
            const int k8 = (kt << 2) + quad;
            short8 b[4];
            #pragma unroll
            for (int f = 0; f < 4; ++f)
                b[f] = *reinterpret_cast<const short8*>(
                    &p.W2Tp[((size_t)k8 * 512 + colw + (f << 4) + l16) << 3]);
            #pragma unroll
            for (int m = 0; m < 2; ++m) {
                const short8 a = *reinterpret_cast<const short8*>(
                    &Hss[(m * 16 + l16) * PAN_STR + (kt << 5) + (quad << 3)]);
                #pragma unroll
                for (int f = 0; f < 4; ++f)
                    acc[m][f] = __builtin_amdgcn_mfma_f32_16x16x32_bf16(a, b[f], acc[m][f], 0, 0, 0);
            }
        }
        __syncthreads();   // (6) all g2 reads done before overwrite
        #pragma unroll
        for (int m = 0; m < 2; ++m)
            #pragma unroll
            for (int f = 0; f < 4; ++f) {
                const int col = colw + (f << 4) + l16;
                #pragma unroll
                for (int r = 0; r < 4; ++r) {
                    const int row = m * 16 + quad * 4 + r;
                    Hss[row * PAN_STR + col] = f2bf(acc[m][f][r]);
                }
            }
        __syncthreads();   // (7) g1' ready

        // ===== phase E: div = rowsum(g1' * (1-h1^2) * u) ; accd/lp regs ========
        {
            float sum = 0.0f;
            #pragma unroll
            for (int j = 0; j < 4; ++j) {
                const int cc = sc + (j << 7);
                const short8 xv = *reinterpret_cast<const short8*>(&Hss[sr * PAN_STR + cc]);
                const short8 hv = *reinterpret_cast<const short8*>(&H1s[sr * PAN_STR + cc]);
                #pragma unroll
                for (int el = 0; el < 8; ++el) {
                    const float x = bf2f((unsigned short)xv[el]);
                    const float h = bf2f((unsigned short)hv[el]);
                    const float uu = bf2f((unsigned short)uv[j][el]);
                    sum += x * (1.0f - h * h) * uu;
                }
            }
            sum += __shfl_xor(sum, 1);
            sum += __shfl_xor(sum, 2);
            sum += __shfl_xor(sum, 4);
            sum += __shfl_xor(sum, 8);
            const float a = wrk * (-sum) + (s0 ? 0.0f : accd_r);
            if (s3) lp_r += a;
            else    accd_r = a;
        }
        // next eval's barrier (1) orders E's H1s/Hss reads vs Z's overwrites
    }

    // ---- write final state ----
    #pragma unroll
    for (int m = 0; m < 2; ++m)
        #pragma unroll
        for (int r = 0; r < 4; ++r)
            p.z[(size_t)(row0 + m * 16 + quad * 4 + r) * 128 + colB] = z_r[m][r];
    if ((tid & 15) == 0) p.lp[row0 + sr] = lp_r;
}

// out[b] = lp[b] - 0.5*||z||^2 - 0.5*128*log(2*pi)
__global__ void final_k(const float* __restrict__ z, const float* __restrict__ lp,
                        float* __restrict__ out) {
    const int tid = threadIdx.x;
    const int row = blockIdx.x * 16 + (tid >> 4);
    const int l16 = tid & 15;
    const float4* zr = (const float4*)&z[(size_t)row * 128 + (l16 << 3)];
    float4 a = zr[0], b = zr[1];
    float s = a.x*a.x + a.y*a.y + a.z*a.z + a.w*a.w
            + b.x*b.x + b.y*b.y + b.z*b.z + b.w*b.w;
    s += __shfl_xor(s, 1);
    s += __shfl_xor(s, 2);
    s += __shfl_xor(s, 4);
    s += __shfl_xor(s, 8);
    if (l16 == 0) out[row] = lp[row] - 0.5f * s - 117.6241322501981f;
}

extern "C" void kernel_launch(void* const* d_in, const int* in_sizes, int n_in,
                              void* d_out, int out_size, void* d_ws, size_t ws_size,
                              hipStream_t stream) {
    (void)n_in; (void)out_size;
    const float* x  = (const float*)d_in[0];
    const float* v  = (const float*)d_in[1];
    const float* W1 = (const float*)d_in[2];
    const float* b1 = (const float*)d_in[3];
    const float* W2 = (const float*)d_in[4];
    const float* b2 = (const float*)d_in[5];
    const float* W3 = (const float*)d_in[6];
    const float* b3 = (const float*)d_in[7];
    float* out = (float*)d_out;
    const int B = in_sizes[0] / DIMV;   // 65536

    auto al = [](size_t s) { return (s + 255) & ~(size_t)255; };
    auto need_for = [&](size_t C) {
        size_t s = 0;
        s += al(C * DIMV * 4);       // z
        s += al(C * 4);              // lp
        s += al(C * HIDV * 2) * 2;   // g3, u
        s += al(128 * 512 * 2) * 3 + al(512 * 512 * 2) * 2; // packed weights
        return s;
    };
    size_t C = 32768;
    while (C > 1024 && need_for(C) > ws_size) C >>= 1;
    if (need_for(C) > ws_size) return;  // cannot run safely in this workspace

    char* w = (char*)d_ws;
    auto alloc = [&](size_t bytes) { char* p = w; w += al(bytes); return p; };
    float* z    = (float*)alloc(C * DIMV * 4);
    float* lp   = (float*)alloc(C * 4);
    unsigned short* g3 = (unsigned short*)alloc(C * HIDV * 2);
    unsigned short* u  = (unsigned short*)alloc(C * HIDV * 2);
    unsigned short* W1zp  = (unsigned short*)alloc(128 * 512 * 2);
    unsigned short* W3p   = (unsigned short*)alloc(512 * 128 * 2);
    unsigned short* W3Tp  = (unsigned short*)alloc(128 * 512 * 2);
    unsigned short* W2p   = (unsigned short*)alloc(512 * 512 * 2);
    unsigned short* W2Tp  = (unsigned short*)alloc(512 * 512 * 2);

    auto pack = [&](const float* src, unsigned short* dst, int K, int N, int ld, int tr) {
        pack_kernel<<<dim3((K * N + 255) / 256), dim3(256), 0, stream>>>(src, dst, K, N, ld, tr);
    };
    pack(W1, W1zp,  128, 512, 512, 0);
    pack(W2, W2p,   512, 512, 512, 0);
    pack(W3, W3p,   512, 128, 128, 0);
    pack(W2, W2Tp,  512, 512, 512, 1);
    pack(W3, W3Tp,  128, 512, 128, 1);

    const int GM128 = (int)C / 128;
    const int GMF   = (int)C / ROWS;

    for (int c0 = 0; c0 < B; c0 += (int)C) {
        const float* xc = x + (size_t)c0 * DIMV;
        const float* vc = v + (size_t)c0 * DIMV;

        // g3 = v @ W3^T ; u = v @ W1z  (once per chunk)
        vg_k<<<dim3(GM128, 2), 256, 0, stream>>>(vc, W3Tp, g3);
        vg_k<<<dim3(GM128, 2), 256, 0, stream>>>(vc, W1zp, u);

        // full 32-step RK4 integration in one persistent dispatch
        OArgs q{};
        q.x = xc;
        q.W1zp = W1zp; q.W2p = W2p; q.W3p = W3p; q.W2Tp = W2Tp;
        q.g3 = g3; q.u = u;
        q.b1 = b1; q.w1t = W1 + 128 * 512; q.b2 = b2; q.b3 = b3;
        q.z = z; q.lp = lp;
        ode_k<<<dim3(GMF), 512, 0, stream>>>(q);

        final_k<<<dim3((int)C / 16), 256, 0, stream>>>(z, lp, out + c0);
    }
}

// Round 7
// 19864.505 us; speedup vs baseline: 1.3514x; 1.3514x over previous
//
#include <hip/hip_runtime.h>

// FFJORD density on MI355X (gfx950). B=65536 rows, DIM=128, HID=512, 32 RK4 steps x 4 evals.
// Round 9: halve L2 weight traffic. R8 counters: spill gone (WRITE 2.1GB->1.9MB) but dur
// unchanged -> the limiter is weight re-fetch: 1.31MB/block/eval x 2 blocks/CU = 2.6MB/eval
// from L2 (~19us at 135GB/s/CU) + 10% L2 miss = the 18GB FETCH. Chip-wide 172GB L2 demand
// = ~10ms floor. Fix: 64-row blocks, 1024 threads, 1 block/CU -> weight bytes per row
// HALVED, but unlike round 6 (8 waves, 2/SIMD, latency-starved) this keeps 16 waves =
// 4 waves/SIMD. Reg budget at the 128 cap: ~105 (acc 32, z/accf 16, g3 16, biases 7,
// frags/addr ~35); u is STREAMED in phase E (not pinned) to keep margin. Volatile biases
// reverted (R8: -7%). Phase structure/panels/barriers identical to R7.
//   Z: h1=tanh(zs@W1z+t*w1t+b1)->H1 | A: h2=tanh(h1@W2+b2)->Hs | B: f=h2@W3+b3, z/accf regs,
//   zs->Zs | C: Hs<-g3-(g3*h2)*h2 | D: Hs<-g2@W2^T | E: div=rowsum(Hs*(1-h1^2)*u)->regs.

#define DIMV 128
#define HIDV 512
#define ROWS 64
#define PAN_STR 536   // panel stride (shorts): 1072B, 16B-aligned, 12-word bank shift/row
#define ZS_STR  136   // 272B, 16B-aligned

typedef float  floatx4 __attribute__((ext_vector_type(4)));
typedef short  short8  __attribute__((ext_vector_type(8)));
typedef unsigned int uint4v __attribute__((ext_vector_type(4)));

static __device__ __forceinline__ unsigned short f2bf(float x) {
    union { float f; unsigned int u; } c; c.f = x;
    unsigned int u = c.u;
    u += 0x7FFFu + ((u >> 16) & 1u);   // round-to-nearest-even
    return (unsigned short)(u >> 16);
}
static __device__ __forceinline__ float bf2f(unsigned short h) {
    union { unsigned int u; float f; } c; c.u = ((unsigned int)h) << 16;
    return c.f;
}
static __device__ __forceinline__ float fast_tanh(float x) {
    x = fminf(8.0f, fmaxf(-8.0f, x));
    float e = exp2f(x * 2.8853900817779268f);            // exp(2x)
    return (e - 1.0f) * __builtin_amdgcn_rcpf(e + 1.0f); // (e-1)/(e+1)
}

// ---- weight packing: dst[(k>>3)*N*8 + n*8 + (k&7)] = bf16(W[k][n]) ------------
__global__ void pack_kernel(const float* __restrict__ src, unsigned short* __restrict__ dst,
                            int K, int N, int ld, int transpose) {
    int i = blockIdx.x * 256 + threadIdx.x;
    if (i >= K * N) return;
    int j  = i & 7;
    int n  = (i >> 3) % N;
    int k8 = (i >> 3) / N;
    int k  = k8 * 8 + j;
    float v = transpose ? src[n * ld + k] : src[k * ld + n];
    dst[i] = f2bf(v);
}

// ---- v-GEMM producer (g3 = v@W3^T, u = v@W1z): 128 rows x 256 cols per WG -----
__global__ __launch_bounds__(256, 2) void vg_k(const float* __restrict__ v,
                                               const unsigned short* __restrict__ Wp,
                                               unsigned short* __restrict__ out0) {
    __shared__ __align__(16) unsigned short As[128 * 72];
    const int tid  = threadIdx.x;
    const int wave = tid >> 6, lane = tid & 63;
    const int quad = lane >> 4, l16 = lane & 15;
    const int row0 = blockIdx.x * 128;
    const int colw = blockIdx.y * 256 + wave * 64;

    floatx4 acc[8][4];
    #pragma unroll
    for (int m = 0; m < 8; ++m)
        #pragma unroll
        for (int f = 0; f < 4; ++f) { floatx4 zz = {0.f,0.f,0.f,0.f}; acc[m][f] = zz; }

    for (int k0 = 0; k0 < 128; k0 += 64) {
        __syncthreads();
        {
            const int r  = tid >> 3;
            const int cc = (tid & 7) << 3;
            #pragma unroll
            for (int i = 0; i < 4; ++i) {
                const int rr = r + (i << 5);
                const size_t base = (size_t)(row0 + rr) * 128 + k0 + cc;
                float vals[8];
                *(float4*)&vals[0] = *(const float4*)&v[base];
                *(float4*)&vals[4] = *(const float4*)&v[base + 4];
                short8 sv;
                #pragma unroll
                for (int j = 0; j < 8; ++j) sv[j] = (short)f2bf(vals[j]);
                *reinterpret_cast<short8*>(&As[rr * 72 + cc]) = sv;
            }
        }
        __syncthreads();
        #pragma unroll
        for (int kt = 0; kt < 2; ++kt) {
            const int k8 = (k0 >> 3) + (kt << 2) + quad;
            short8 b[4];
            #pragma unroll
            for (int f = 0; f < 4; ++f)
                b[f] = *reinterpret_cast<const short8*>(
                    &Wp[((size_t)k8 * 512 + colw + (f << 4) + l16) << 3]);
            #pragma unroll
            for (int m = 0; m < 8; ++m) {
                const short8 a = *reinterpret_cast<const short8*>(
                    &As[(m * 16 + l16) * 72 + (kt << 5) + (quad << 3)]);
                #pragma unroll
                for (int f = 0; f < 4; ++f)
                    acc[m][f] = __builtin_amdgcn_mfma_f32_16x16x32_bf16(a, b[f], acc[m][f], 0, 0, 0);
            }
        }
    }
    #pragma unroll
    for (int m = 0; m < 8; ++m)
        #pragma unroll
        for (int f = 0; f < 4; ++f) {
            const int col = colw + (f << 4) + l16;
            #pragma unroll
            for (int r = 0; r < 4; ++r) {
                const int row = row0 + m * 16 + quad * 4 + r;
                out0[(size_t)row * 512 + col] = f2bf(acc[m][f][r]);
            }
        }
}

// ---- persistent integrator ----------------------------------------------------
struct OArgs {
    const float* x;              // fp32 input chunk [C,128]
    const unsigned short* W1zp;  // packed (K=128,N=512)
    const unsigned short* W2p;   // packed (K=512,N=512)
    const unsigned short* W3p;   // packed (K=512,N=128)
    const unsigned short* W2Tp;  // packed (K=512,N=512)
    const unsigned short* g3;    // bf16 [C,512]  (per-chunk constant, pinned)
    const unsigned short* u;     // bf16 [C,512]  (per-chunk constant, streamed in E)
    const float* b1;
    const float* w1t;            // W1 row 128 (t coefficients)
    const float* b2;
    const float* b3;
    float* z;                    // fp32 [C,128] out (for final_k)
    float* lp;                   // fp32 [C]
};

__global__ __launch_bounds__(1024, 4) void ode_k(OArgs p) {
    __shared__ __align__(16) unsigned short H1s[ROWS * PAN_STR]; // 68.6 KB h1 panel
    __shared__ __align__(16) unsigned short Hss[ROWS * PAN_STR]; // 68.6 KB h2/g2/g1' panel
    __shared__ __align__(16) unsigned short Zss[ROWS * ZS_STR];  // 17.4 KB zs panel
    const int tid  = threadIdx.x;
    const int wave = tid >> 6, lane = tid & 63;
    const int quad = lane >> 4, l16 = lane & 15;
    const int row0 = blockIdx.x * ROWS;
    const int colw = wave << 5;            // phases Z/A/D: 32 cols per wave (16 waves)
    const int sr = tid >> 4;               // streaming row 0..63 (16 threads/row)
    const int sc = (tid & 15) << 3;        // streaming col-base (shorts), 128 cols/pass
    const size_t gbase = (size_t)(row0 + sr) * 512;
    const int colB = ((wave & 7) << 4) + l16;   // phase B column (0..127)
    const int rowB = (wave >> 3) << 5;          // phase B row half (0 or 32)

    // ---- per-chunk constants pinned in registers ----
    short8 g3v[4];
    #pragma unroll
    for (int j = 0; j < 4; ++j)
        g3v[j] = *reinterpret_cast<const short8*>(&p.g3[gbase + sc + (j << 7)]);
    float b1v[2], w1tv[2], b2v[2];
    #pragma unroll
    for (int f = 0; f < 2; ++f) {
        const int col = colw + (f << 4) + l16;
        b1v[f] = p.b1[col]; w1tv[f] = p.w1t[col]; b2v[f] = p.b2[col];
    }
    const float b3v = p.b3[colB];

    // ---- state in registers (phase-B mapping: row=rowB+m*16+quad*4+r, col=colB) ----
    float z_r[2][4];
    #pragma unroll
    for (int m = 0; m < 2; ++m)
        #pragma unroll
        for (int r = 0; r < 4; ++r) {
            const int row = rowB + m * 16 + quad * 4 + r;
            const float val = p.x[(size_t)(row0 + row) * 128 + colB];
            z_r[m][r] = val;
            Zss[row * ZS_STR + colB] = f2bf(val);
        }
    float accf_r[2][4];
    float accd_r = 0.0f, lp_r = 0.0f;      // valid on tid&15==0 lanes

    const float dt = 1.0f / 32.0f;
    floatx4 acc[4][2];                     // shared by phases Z/A/D

    for (int e = 0; e < 128; ++e) {
        const int s = e & 3;
        const int step = e >> 2;
        const bool s0 = (s == 0), s3 = (s == 3);
        const float tph  = (s == 0) ? 0.0f : (s == 3 ? dt : 0.5f * dt);
        const float t    = (float)step * dt + tph;
        const float wrk  = (s == 1 || s == 2) ? (dt / 3.0f) : (dt / 6.0f);
        const float cnext = (s <= 1) ? 0.5f * dt : (s == 2 ? dt : 0.0f);

        __syncthreads();   // (1) close prev eval: E's H1s/Hss reads done; Zss writes visible

        // ===== phase Z: h1 = tanh(zs @ W1z + t*w1t + b1) -> H1s ================
        #pragma unroll
        for (int m = 0; m < 4; ++m)
            #pragma unroll
            for (int f = 0; f < 2; ++f) { floatx4 zz = {0.f,0.f,0.f,0.f}; acc[m][f] = zz; }
        #pragma unroll
        for (int kt = 0; kt < 4; ++kt) {
            const int k8 = (kt << 2) + quad;
            short8 b[2];
            #pragma unroll
            for (int f = 0; f < 2; ++f)
                b[f] = *reinterpret_cast<const short8*>(
                    &p.W1zp[((size_t)k8 * 512 + colw + (f << 4) + l16) << 3]);
            #pragma unroll
            for (int m = 0; m < 4; ++m) {
                const short8 a = *reinterpret_cast<const short8*>(
                    &Zss[(m * 16 + l16) * ZS_STR + (kt << 5) + (quad << 3)]);
                #pragma unroll
                for (int f = 0; f < 2; ++f)
                    acc[m][f] = __builtin_amdgcn_mfma_f32_16x16x32_bf16(a, b[f], acc[m][f], 0, 0, 0);
            }
        }
        #pragma unroll
        for (int m = 0; m < 4; ++m)
            #pragma unroll
            for (int f = 0; f < 2; ++f) {
                const int col = colw + (f << 4) + l16;
                const float bias = b1v[f] + t * w1tv[f];
                #pragma unroll
                for (int r = 0; r < 4; ++r) {
                    const int row = m * 16 + quad * 4 + r;
                    H1s[row * PAN_STR + col] = f2bf(fast_tanh(acc[m][f][r] + bias));
                }
            }
        __syncthreads();   // (2) H1s ready

        // ===== phase A: h2 = tanh(h1 @ W2 + b2) -> Hss =========================
        #pragma unroll
        for (int m = 0; m < 4; ++m)
            #pragma unroll
            for (int f = 0; f < 2; ++f) { floatx4 zz = {0.f,0.f,0.f,0.f}; acc[m][f] = zz; }
        #pragma unroll 4
        for (int kt = 0; kt < 16; ++kt) {
            const int k8 = (kt << 2) + quad;
            short8 b[2];
            #pragma unroll
            for (int f = 0; f < 2; ++f)
                b[f] = *reinterpret_cast<const short8*>(
                    &p.W2p[((size_t)k8 * 512 + colw + (f << 4) + l16) << 3]);
            #pragma unroll
            for (int m = 0; m < 4; ++m) {
                const short8 a = *reinterpret_cast<const short8*>(
                    &H1s[(m * 16 + l16) * PAN_STR + (kt << 5) + (quad << 3)]);
                #pragma unroll
                for (int f = 0; f < 2; ++f)
                    acc[m][f] = __builtin_amdgcn_mfma_f32_16x16x32_bf16(a, b[f], acc[m][f], 0, 0, 0);
            }
        }
        #pragma unroll
        for (int m = 0; m < 4; ++m)
            #pragma unroll
            for (int f = 0; f < 2; ++f) {
                const int col = colw + (f << 4) + l16;
                #pragma unroll
                for (int r = 0; r < 4; ++r) {
                    const int row = m * 16 + quad * 4 + r;
                    Hss[row * PAN_STR + col] = f2bf(fast_tanh(acc[m][f][r] + b2v[f]));
                }
            }
        __syncthreads();   // (3) Hss (h2) ready

        // ===== phase B: f = h2 @ W3 + b3 ; z/accf regs ; zs -> Zss =============
        {
            floatx4 accb[2];
            #pragma unroll
            for (int m = 0; m < 2; ++m) { floatx4 zz = {0.f,0.f,0.f,0.f}; accb[m] = zz; }
            #pragma unroll 4
            for (int kt = 0; kt < 16; ++kt) {
                const int k8 = (kt << 2) + quad;
                const short8 b = *reinterpret_cast<const short8*>(
                    &p.W3p[((size_t)k8 * 128 + colB) << 3]);
                #pragma unroll
                for (int m = 0; m < 2; ++m) {
                    const short8 a = *reinterpret_cast<const short8*>(
                        &Hss[(rowB + m * 16 + l16) * PAN_STR + (kt << 5) + (quad << 3)]);
                    accb[m] = __builtin_amdgcn_mfma_f32_16x16x32_bf16(a, b, accb[m], 0, 0, 0);
                }
            }
            #pragma unroll
            for (int m = 0; m < 2; ++m) {
                #pragma unroll
                for (int r = 0; r < 4; ++r) {
                    const int row = rowB + m * 16 + quad * 4 + r;
                    const float x = accb[m][r] + b3v;
                    const float a = wrk * x + (s0 ? 0.0f : accf_r[m][r]);
                    if (s3) {
                        z_r[m][r] += a;                       // z += dt/6 * sum(k)
                        Zss[row * ZS_STR + colB] = f2bf(z_r[m][r]);
                    } else {
                        accf_r[m][r] = a;
                        Zss[row * ZS_STR + colB] = f2bf(z_r[m][r] + cnext * x);
                    }
                }
            }
        }
        __syncthreads();   // (4) all h2 reads done before in-place C

        // ===== phase C: Hss <- g2 = g3 - (g3*h2)*h2  (pinned g3 regs) ==========
        #pragma unroll
        for (int j = 0; j < 4; ++j) {
            const int cc = sc + (j << 7);
            const short8 hv = *reinterpret_cast<const short8*>(&Hss[sr * PAN_STR + cc]);
            short8 ov;
            #pragma unroll
            for (int el = 0; el < 8; ++el) {
                const float h = bf2f((unsigned short)hv[el]);
                const float g = bf2f((unsigned short)g3v[j][el]);
                const float gh = g * h;
                ov[el] = (short)f2bf(fmaf(-gh, h, g));
            }
            *reinterpret_cast<short8*>(&Hss[sr * PAN_STR + cc]) = ov;
        }
        __syncthreads();   // (5) g2 ready

        // ===== phase D: Hss <- g2 @ W2^T ========================================
        #pragma unroll
        for (int m = 0; m < 4; ++m)
            #pragma unroll
            for (int f = 0; f < 2; ++f) { floatx4 zz = {0.f,0.f,0.f,0.f}; acc[m][f] = zz; }
        #pragma unroll 4
        for (int kt = 0; kt < 16; ++kt) {
            const int k8 = (kt << 2) + quad;
            short8 b[2];
            #pragma unroll
            for (int f = 0; f < 2; ++f)
                b[f] = *reinterpret_cast<const short8*>(
                    &p.W2Tp[((size_t)k8 * 512 + colw + (f << 4) + l16) << 3]);
            #pragma unroll
            for (int m = 0; m < 4; ++m) {
                const short8 a = *reinterpret_cast<const short8*>(
                    &Hss[(m * 16 + l16) * PAN_STR + (kt << 5) + (quad << 3)]);
                #pragma unroll
                for (int f = 0; f < 2; ++f)
                    acc[m][f] = __builtin_amdgcn_mfma_f32_16x16x32_bf16(a, b[f], acc[m][f], 0, 0, 0);
            }
        }
        __syncthreads();   // (6) all g2 reads done before overwrite
        #pragma unroll
        for (int m = 0; m < 4; ++m)
            #pragma unroll
            for (int f = 0; f < 2; ++f) {
                const int col = colw + (f << 4) + l16;
                #pragma unroll
                for (int r = 0; r < 4; ++r) {
                    const int row = m * 16 + quad * 4 + r;
                    Hss[row * PAN_STR + col] = f2bf(acc[m][f][r]);
                }
            }
        __syncthreads();   // (7) g1' ready

        // ===== phase E: div = rowsum(g1' * (1-h1^2) * u) ; u streamed from L2 ==
        {
            float sum = 0.0f;
            #pragma unroll
            for (int j = 0; j < 4; ++j) {
                const int cc = sc + (j << 7);
                const short8 xv = *reinterpret_cast<const short8*>(&Hss[sr * PAN_STR + cc]);
                const short8 hv = *reinterpret_cast<const short8*>(&H1s[sr * PAN_STR + cc]);
                const short8 uv = *reinterpret_cast<const short8*>(&p.u[gbase + cc]);
                #pragma unroll
                for (int el = 0; el < 8; ++el) {
                    const float x = bf2f((unsigned short)xv[el]);
                    const float h = bf2f((unsigned short)hv[el]);
                    const float uu = bf2f((unsigned short)uv[el]);
                    sum += x * (1.0f - h * h) * uu;
                }
            }
            sum += __shfl_xor(sum, 1);
            sum += __shfl_xor(sum, 2);
            sum += __shfl_xor(sum, 4);
            sum += __shfl_xor(sum, 8);
            const float a = wrk * (-sum) + (s0 ? 0.0f : accd_r);
            if (s3) lp_r += a;
            else    accd_r = a;
        }
        // next eval's barrier (1) orders E's H1s/Hss reads vs Z's overwrites
    }

    // ---- write final state ----
    #pragma unroll
    for (int m = 0; m < 2; ++m)
        #pragma unroll
        for (int r = 0; r < 4; ++r)
            p.z[(size_t)(row0 + rowB + m * 16 + quad * 4 + r) * 128 + colB] = z_r[m][r];
    if ((tid & 15) == 0) p.lp[row0 + sr] = lp_r;
}

// out[b] = lp[b] - 0.5*||z||^2 - 0.5*128*log(2*pi)
__global__ void final_k(const float* __restrict__ z, const float* __restrict__ lp,
                        float* __restrict__ out) {
    const int tid = threadIdx.x;
    const int row = blockIdx.x * 16 + (tid >> 4);
    const int l16 = tid & 15;
    const float4* zr = (const float4*)&z[(size_t)row * 128 + (l16 << 3)];
    float4 a = zr[0], b = zr[1];
    float s = a.x*a.x + a.y*a.y + a.z*a.z + a.w*a.w
            + b.x*b.x + b.y*b.y + b.z*b.z + b.w*b.w;
    s += __shfl_xor(s, 1);
    s += __shfl_xor(s, 2);
    s += __shfl_xor(s, 4);
    s += __shfl_xor(s, 8);
    if (l16 == 0) out[row] = lp[row] - 0.5f * s - 117.6241322501981f;
}

extern "C" void kernel_launch(void* const* d_in, const int* in_sizes, int n_in,
                              void* d_out, int out_size, void* d_ws, size_t ws_size,
                              hipStream_t stream) {
    (void)n_in; (void)out_size;
    const float* x  = (const float*)d_in[0];
    const float* v  = (const float*)d_in[1];
    const float* W1 = (const float*)d_in[2];
    const float* b1 = (const float*)d_in[3];
    const float* W2 = (const float*)d_in[4];
    const float* b2 = (const float*)d_in[5];
    const float* W3 = (const float*)d_in[6];
    const float* b3 = (const float*)d_in[7];
    float* out = (float*)d_out;
    const int B = in_sizes[0] / DIMV;   // 65536

    auto al = [](size_t s) { return (s + 255) & ~(size_t)255; };
    auto need_for = [&](size_t C) {
        size_t s = 0;
        s += al(C * DIMV * 4);       // z
        s += al(C * 4);              // lp
        s += al(C * HIDV * 2) * 2;   // g3, u
        s += al(128 * 512 * 2) * 3 + al(512 * 512 * 2) * 2; // packed weights
        return s;
    };
    size_t C = 32768;
    while (C > 1024 && need_for(C) > ws_size) C >>= 1;
    if (need_for(C) > ws_size) return;  // cannot run safely in this workspace

    char* w = (char*)d_ws;
    auto alloc = [&](size_t bytes) { char* p = w; w += al(bytes); return p; };
    float* z    = (float*)alloc(C * DIMV * 4);
    float* lp   = (float*)alloc(C * 4);
    unsigned short* g3 = (unsigned short*)alloc(C * HIDV * 2);
    unsigned short* u  = (unsigned short*)alloc(C * HIDV * 2);
    unsigned short* W1zp  = (unsigned short*)alloc(128 * 512 * 2);
    unsigned short* W3p   = (unsigned short*)alloc(512 * 128 * 2);
    unsigned short* W3Tp  = (unsigned short*)alloc(128 * 512 * 2);
    unsigned short* W2p   = (unsigned short*)alloc(512 * 512 * 2);
    unsigned short* W2Tp  = (unsigned short*)alloc(512 * 512 * 2);

    auto pack = [&](const float* src, unsigned short* dst, int K, int N, int ld, int tr) {
        pack_kernel<<<dim3((K * N + 255) / 256), dim3(256), 0, stream>>>(src, dst, K, N, ld, tr);
    };
    pack(W1, W1zp,  128, 512, 512, 0);
    pack(W2, W2p,   512, 512, 512, 0);
    pack(W3, W3p,   512, 128, 128, 0);
    pack(W2, W2Tp,  512, 512, 512, 1);
    pack(W1, W3Tp,  512, 128, 512, 1);  // placeholder overwritten below (keep slot warm)
    pack(W3, W3Tp,  128, 512, 128, 1);

    const int GM128 = (int)C / 128;
    const int GMF   = (int)C / ROWS;

    for (int c0 = 0; c0 < B; c0 += (int)C) {
        const float* xc = x + (size_t)c0 * DIMV;
        const float* vc = v + (size_t)c0 * DIMV;

        // g3 = v @ W3^T ; u = v @ W1z  (once per chunk)
        vg_k<<<dim3(GM128, 2), 256, 0, stream>>>(vc, W3Tp, g3);
        vg_k<<<dim3(GM128, 2), 256, 0, stream>>>(vc, W1zp, u);

        // full 32-step RK4 integration in one persistent dispatch
        OArgs q{};
        q.x = xc;
        q.W1zp = W1zp; q.W2p = W2p; q.W3p = W3p; q.W2Tp = W2Tp;
        q.g3 = g3; q.u = u;
        q.b1 = b1; q.w1t = W1 + 128 * 512; q.b2 = b2; q.b3 = b3;
        q.z = z; q.lp = lp;
        ode_k<<<dim3(GMF), 1024, 0, stream>>>(q);

        final_k<<<dim3((int)C / 16), 256, 0, stream>>>(z, lp, out + c0);
    }
}